// Round 7
// baseline (1817.574 us; speedup 1.0000x reference)
//
#include <hip/hip_runtime.h>

// GRU: B=128, T=2048, H=128.
// Kernel 1 (gru_proj): xz/xr/xh = x @ W^T + b via bf16 MFMA 16x16x32.
//   xz,xr packed as 2x bf16 into d_out words (consumed then overwritten by h),
//   xh as bf16 into d_ws.
// Kernel 2 (gru_rec2): TWO independent batches per block (b, b+64), 64 blocks,
//   8 waves x 16 units per batch. Broadcast-A MFMA matvecs (k-reduce inside
//   MFMA). The two batches' dependency chains interleave inside one barrier
//   window -> fixed per-phase costs (barrier sync, LDS latency, LDS pipe
//   serialization) are amortized 2x. U fragments shared across batches.
//   2 lgkm-only barriers per step-pair; 2-deep global prefetch +
//   fire-and-forget h stores (vmcnt never drained in loop).

#define T_LEN 2048
#define H_DIM 128

typedef __attribute__((ext_vector_type(8))) __bf16 bf16x8;
typedef __attribute__((ext_vector_type(4))) float f32x4;

// raw barrier: drains LDS ops (cross-wave visibility) but NOT vmcnt. [m201]
#define BARRIER() asm volatile("s_waitcnt lgkmcnt(0)\n\ts_barrier" ::: "memory")

__device__ __forceinline__ unsigned short f2bf_bits(float f){
  __bf16 b = (__bf16)f;                     // fptrunc, RNE
  return __builtin_bit_cast(unsigned short, b);
}
__device__ __forceinline__ float bf2f(unsigned short s){
  unsigned int u = ((unsigned int)s) << 16;
  return __builtin_bit_cast(float, u);
}
__device__ __forceinline__ unsigned int pack_bf16_rne(float lo, float hi){
  return (unsigned int)f2bf_bits(lo) | (((unsigned int)f2bf_bits(hi)) << 16);
}
// hardware v_exp_f32 / v_rcp_f32 (no precise-division sequence)
__device__ __forceinline__ float sigm(float x){
  float e = __builtin_amdgcn_exp2f(-1.4426950408889634f * x);
  return __builtin_amdgcn_rcpf(1.0f + e);
}
__device__ __forceinline__ float tanh_fast(float x){
  float e = __builtin_amdgcn_exp2f(2.8853900817779268f * x);  // e^(2x)
  return 1.0f - 2.0f * __builtin_amdgcn_rcpf(e + 1.0f);       // inf-safe
}
// lane <- lane^1 value (quad_perm [1,0,3,2] = 0xB1); run in ALL lanes
__device__ __forceinline__ float dpp_xor1(float x){
  int r = __builtin_amdgcn_update_dpp(0, __builtin_bit_cast(int, x),
                                      0xB1, 0xF, 0xF, true);
  return __builtin_bit_cast(float, r);
}

// ---------------- projection GEMM (unchanged, verified) ----------------

__device__ __forceinline__ void stage_mat128(const float* __restrict__ src,
                                             __bf16 (*dst)[136], int tid){
  #pragma unroll
  for (int rep = 0; rep < 8; ++rep){
    int fi = rep * 2048 + tid * 4;
    float4 v = *reinterpret_cast<const float4*>(src + fi);
    int m = fi >> 7;
    int k = fi & 127;
    unsigned long long pk =
        (unsigned long long)f2bf_bits(v.x)
      | ((unsigned long long)f2bf_bits(v.y) << 16)
      | ((unsigned long long)f2bf_bits(v.z) << 32)
      | ((unsigned long long)f2bf_bits(v.w) << 48);
    *reinterpret_cast<unsigned long long*>(&dst[m][k]) = pk;
  }
}

__global__ __launch_bounds__(512, 2) void gru_proj(
    const float* __restrict__ x,
    const float* __restrict__ Wz, const float* __restrict__ Wr, const float* __restrict__ Wh,
    const float* __restrict__ bz, const float* __restrict__ br, const float* __restrict__ bh,
    unsigned int* __restrict__ out_zr, unsigned short* __restrict__ out_h)
{
  __shared__ __bf16 xs[128][136];
  __shared__ __bf16 wsh[3][128][136];

  const int tid = threadIdx.x;
  const long Mbase = (long)blockIdx.x * 128;

  stage_mat128(x + Mbase * H_DIM, xs, tid);
  stage_mat128(Wz, wsh[0], tid);
  stage_mat128(Wr, wsh[1], tid);
  stage_mat128(Wh, wsh[2], tid);
  __syncthreads();

  const int w  = tid >> 6, l = tid & 63;
  const int ml = l & 15;
  const int kl = (l >> 4) * 8;
  const int n  = w * 16 + ml;

  bf16x8 bfr[3][4];
  #pragma unroll
  for (int g = 0; g < 3; ++g)
    #pragma unroll
    for (int kk = 0; kk < 4; ++kk)
      bfr[g][kk] = *reinterpret_cast<const bf16x8*>(&wsh[g][n][kk * 32 + kl]);

  const float bzv = bz[n], brv = br[n], bhv = bh[n];

  f32x4 acc[8][3];
  #pragma unroll
  for (int mt = 0; mt < 8; ++mt)
    #pragma unroll
    for (int g = 0; g < 3; ++g)
      acc[mt][g] = (f32x4){0.f, 0.f, 0.f, 0.f};

  #pragma unroll
  for (int mt = 0; mt < 8; ++mt){
    #pragma unroll
    for (int kk = 0; kk < 4; ++kk){
      bf16x8 a = *reinterpret_cast<const bf16x8*>(&xs[mt * 16 + ml][kk * 32 + kl]);
      acc[mt][0] = __builtin_amdgcn_mfma_f32_16x16x32_bf16(a, bfr[0][kk], acc[mt][0], 0, 0, 0);
      acc[mt][1] = __builtin_amdgcn_mfma_f32_16x16x32_bf16(a, bfr[1][kk], acc[mt][1], 0, 0, 0);
      acc[mt][2] = __builtin_amdgcn_mfma_f32_16x16x32_bf16(a, bfr[2][kk], acc[mt][2], 0, 0, 0);
    }
  }

  #pragma unroll
  for (int mt = 0; mt < 8; ++mt){
    #pragma unroll
    for (int p = 0; p < 4; ++p){
      long row = Mbase + mt * 16 + (l >> 4) * 4 + p;
      float vz = acc[mt][0][p] + bzv;
      float vr = acc[mt][1][p] + brv;
      float vh = acc[mt][2][p] + bhv;
      unsigned int word = (unsigned int)f2bf_bits(vz)
                        | (((unsigned int)f2bf_bits(vr)) << 16);
      out_zr[row * H_DIM + n] = word;
      out_h [row * H_DIM + n] = f2bf_bits(vh);
    }
  }
}

// -------- recurrence: broadcast-A MFMA, 8 waves, 2 batches/block --------

__device__ __forceinline__ bf16x8 ld_u_frag(const float* p){
  float4 a = *reinterpret_cast<const float4*>(p);
  float4 b = *reinterpret_cast<const float4*>(p + 4);
  bf16x8 r;
  r[0]=(__bf16)a.x; r[1]=(__bf16)a.y; r[2]=(__bf16)a.z; r[3]=(__bf16)a.w;
  r[4]=(__bf16)b.x; r[5]=(__bf16)b.y; r[6]=(__bf16)b.z; r[7]=(__bf16)b.w;
  return r;
}

#define MFMA(A, B, C) __builtin_amdgcn_mfma_f32_16x16x32_bf16(A, B, C, 0, 0, 0)

__device__ __forceinline__ void gru_step2(
    int t, int ubP, int ubQ, int lenP, int lenQ, int g8, int l, int w,
    const bf16x8* ufz, const bf16x8* ufr, const bf16x8* ufh,
    __bf16* hxP, __bf16* rhxP, __bf16* hxQ, __bf16* rhxQ,
    const unsigned int* xzr, const unsigned short* xh, float* out,
    unsigned int& zrP, unsigned short& xhP, float& hP,
    unsigned int& zrQ, unsigned short& xhQ, float& hQ)
{
  const f32x4 zero = (f32x4){0.f, 0.f, 0.f, 0.f};
  const int tp = (t + 2 < T_LEN) ? t + 2 : T_LEN - 1;
  const bool wr = ((l & 1) == 0) & (l < 16);

  // ---- phase A: r gates for BOTH batches ----
  // issue all 8 ds_reads first; MFMAs/VALU interleave as data lands
  bf16x8 aP0 = *reinterpret_cast<const bf16x8*>(&hxP[      g8 * 8]);
  bf16x8 aP1 = *reinterpret_cast<const bf16x8*>(&hxP[32  + g8 * 8]);
  bf16x8 aP2 = *reinterpret_cast<const bf16x8*>(&hxP[64  + g8 * 8]);
  bf16x8 aP3 = *reinterpret_cast<const bf16x8*>(&hxP[96  + g8 * 8]);
  bf16x8 aQ0 = *reinterpret_cast<const bf16x8*>(&hxQ[      g8 * 8]);
  bf16x8 aQ1 = *reinterpret_cast<const bf16x8*>(&hxQ[32  + g8 * 8]);
  bf16x8 aQ2 = *reinterpret_cast<const bf16x8*>(&hxQ[64  + g8 * 8]);
  bf16x8 aQ3 = *reinterpret_cast<const bf16x8*>(&hxQ[96  + g8 * 8]);

  f32x4 rP0 = MFMA(aP0, ufr[0], zero);
  f32x4 rP1 = MFMA(aP1, ufr[1], zero);
  f32x4 rP2 = MFMA(aP2, ufr[2], zero);
  f32x4 rP3 = MFMA(aP3, ufr[3], zero);
  f32x4 rQ0 = MFMA(aQ0, ufr[0], zero);
  f32x4 rQ1 = MFMA(aQ1, ufr[1], zero);
  f32x4 rQ2 = MFMA(aQ2, ufr[2], zero);
  f32x4 rQ3 = MFMA(aQ3, ufr[3], zero);

  float xzvP = bf2f((unsigned short)(zrP & 0xffffu));   // keep for phase B
  float xrvP = bf2f((unsigned short)(zrP >> 16));
  float xzvQ = bf2f((unsigned short)(zrQ & 0xffffu));
  float xrvQ = bf2f((unsigned short)(zrQ >> 16));
  zrP = xzr[ubP + tp * H_DIM];                           // refill for t+2
  zrQ = xzr[ubQ + tp * H_DIM];

  float rgP = sigm(xrvP + ((rP0[0] + rP1[0]) + (rP2[0] + rP3[0])));
  float rhP = rgP * hP;
  float rhnP = dpp_xor1(rhP);                            // all lanes (exec!)
  if (wr)
    *reinterpret_cast<unsigned int*>(&rhxP[w * 16 + (l & 14)]) = pack_bf16_rne(rhP, rhnP);
  float rgQ = sigm(xrvQ + ((rQ0[0] + rQ1[0]) + (rQ2[0] + rQ3[0])));
  float rhQ = rgQ * hQ;
  float rhnQ = dpp_xor1(rhQ);
  if (wr)
    *reinterpret_cast<unsigned int*>(&rhxQ[w * 16 + (l & 14)]) = pack_bf16_rne(rhQ, rhnQ);
  BARRIER();                                             // rh visible

  // ---- phase B: z (register frags; issues under rh reads) + h~ + update ----
  bf16x8 bP0 = *reinterpret_cast<const bf16x8*>(&rhxP[      g8 * 8]);
  bf16x8 bP1 = *reinterpret_cast<const bf16x8*>(&rhxP[32  + g8 * 8]);
  bf16x8 bP2 = *reinterpret_cast<const bf16x8*>(&rhxP[64  + g8 * 8]);
  bf16x8 bP3 = *reinterpret_cast<const bf16x8*>(&rhxP[96  + g8 * 8]);
  bf16x8 bQ0 = *reinterpret_cast<const bf16x8*>(&rhxQ[      g8 * 8]);
  bf16x8 bQ1 = *reinterpret_cast<const bf16x8*>(&rhxQ[32  + g8 * 8]);
  bf16x8 bQ2 = *reinterpret_cast<const bf16x8*>(&rhxQ[64  + g8 * 8]);
  bf16x8 bQ3 = *reinterpret_cast<const bf16x8*>(&rhxQ[96  + g8 * 8]);

  f32x4 zP0 = MFMA(aP0, ufz[0], zero);                   // register-only inputs
  f32x4 zP1 = MFMA(aP1, ufz[1], zero);
  f32x4 zP2 = MFMA(aP2, ufz[2], zero);
  f32x4 zP3 = MFMA(aP3, ufz[3], zero);
  f32x4 zQ0 = MFMA(aQ0, ufz[0], zero);
  f32x4 zQ1 = MFMA(aQ1, ufz[1], zero);
  f32x4 zQ2 = MFMA(aQ2, ufz[2], zero);
  f32x4 zQ3 = MFMA(aQ3, ufz[3], zero);

  f32x4 hP0 = MFMA(bP0, ufh[0], zero);
  f32x4 hP1 = MFMA(bP1, ufh[1], zero);
  f32x4 hP2 = MFMA(bP2, ufh[2], zero);
  f32x4 hP3 = MFMA(bP3, ufh[3], zero);
  f32x4 hQ0 = MFMA(bQ0, ufh[0], zero);
  f32x4 hQ1 = MFMA(bQ1, ufh[1], zero);
  f32x4 hQ2 = MFMA(bQ2, ufh[2], zero);
  f32x4 hQ3 = MFMA(bQ3, ufh[3], zero);

  float zgP = sigm(xzvP + ((zP0[0] + zP1[0]) + (zP2[0] + zP3[0])));
  float hcP = tanh_fast(bf2f(xhP) + ((hP0[0] + hP1[0]) + (hP2[0] + hP3[0])));
  float hnP = fmaf(zgP, hcP - hP, hP);                   // (1-z)h + z*hc
  hP = hnP;
  float hnnP = dpp_xor1(hnP);
  if (wr)
    *reinterpret_cast<unsigned int*>(&hxP[w * 16 + (l & 14)]) = pack_bf16_rne(hnP, hnnP);

  float zgQ = sigm(xzvQ + ((zQ0[0] + zQ1[0]) + (zQ2[0] + zQ3[0])));
  float hcQ = tanh_fast(bf2f(xhQ) + ((hQ0[0] + hQ1[0]) + (hQ2[0] + hQ3[0])));
  float hnQ = fmaf(zgQ, hcQ - hQ, hQ);
  hQ = hnQ;
  float hnnQ = dpp_xor1(hnQ);
  if (wr)
    *reinterpret_cast<unsigned int*>(&hxQ[w * 16 + (l & 14)]) = pack_bf16_rne(hnQ, hnnQ);

  if (l < 16){
    if (t < lenP) out[ubP + t * H_DIM] = hnP;            // fire-and-forget
    if (t < lenQ) out[ubQ + t * H_DIM] = hnQ;
  }
  xhP = xh[ubP + tp * H_DIM];                            // refill for t+2
  xhQ = xh[ubQ + tp * H_DIM];
  BARRIER();                                             // h' visible
}

__global__ __launch_bounds__(512, 1) void gru_rec2(
    const float* __restrict__ Uz, const float* __restrict__ Ur, const float* __restrict__ Uh,
    const int* __restrict__ lengths,
    const unsigned int* xzr,            // aliases `out` (packed bf16 xz|xr)
    const unsigned short* __restrict__ xh,
    float* out)
{
  __shared__ __align__(16) __bf16 hxP[H_DIM];
  __shared__ __align__(16) __bf16 rhxP[H_DIM];
  __shared__ __align__(16) __bf16 hxQ[H_DIM];
  __shared__ __align__(16) __bf16 rhxQ[H_DIM];

  const int tid = threadIdx.x;
  const int w = tid >> 6, l = tid & 63;
  const int g8 = l >> 4;                // k-slice within each 32-k block
  const int u  = w * 16 + (l & 15);     // owned unit (C col)
  const int bP = blockIdx.x;
  const int bQ = blockIdx.x + 64;
  const int lenP = lengths[bP], lenQ = lengths[bQ];
  const int maxlen = lenP > lenQ ? lenP : lenQ;

  // U B-fragments, SHARED by both batches: 48 VGPRs
  bf16x8 ufz[4], ufr[4], ufh[4];
  #pragma unroll
  for (int kk = 0; kk < 4; ++kk){
    const int ko = kk * 32 + g8 * 8;
    ufz[kk] = ld_u_frag(Uz + u * H_DIM + ko);
    ufr[kk] = ld_u_frag(Ur + u * H_DIM + ko);
    ufh[kk] = ld_u_frag(Uh + u * H_DIM + ko);
  }

  if (tid < 64){                                         // h0 = 0
    reinterpret_cast<unsigned int*>(hxP)[tid] = 0u;
    reinterpret_cast<unsigned int*>(hxQ)[tid] = 0u;
  }
  float hP = 0.f, hQ = 0.f;
  __syncthreads();

  const int ubP = bP * (T_LEN * H_DIM) + u;
  const int ubQ = bQ * (T_LEN * H_DIM) + u;

  // 2-deep prefetch, named regs
  unsigned int  zrPA = xzr[ubP],         zrPB = xzr[ubP + H_DIM];
  unsigned int  zrQA = xzr[ubQ],         zrQB = xzr[ubQ + H_DIM];
  unsigned short xhPA = xh[ubP],         xhPB = xh[ubP + H_DIM];
  unsigned short xhQA = xh[ubQ],         xhQB = xh[ubQ + H_DIM];

  int t = 0;
  for (; t + 1 < maxlen; t += 2){
    gru_step2(t,   ubP, ubQ, lenP, lenQ, g8, l, w, ufz, ufr, ufh,
              hxP, rhxP, hxQ, rhxQ, xzr, xh, out,
              zrPA, xhPA, hP, zrQA, xhQA, hQ);
    gru_step2(t+1, ubP, ubQ, lenP, lenQ, g8, l, w, ufz, ufr, ufh,
              hxP, rhxP, hxQ, rhxQ, xzr, xh, out,
              zrPB, xhPB, hP, zrQB, xhQB, hQ);
  }
  if (t < maxlen){
    gru_step2(t,   ubP, ubQ, lenP, lenQ, g8, l, w, ufz, ufr, ufh,
              hxP, rhxP, hxQ, rhxQ, xzr, xh, out,
              zrPA, xhPA, hP, zrQA, xhQA, hQ);
  }

  // masked region: exact zeros for t >= len (disjoint from h-stores)
  const long baseP = (long)bP * (T_LEN * H_DIM);
  for (long i = (long)lenP * H_DIM + tid * 4; i < (long)T_LEN * H_DIM; i += 512 * 4){
    *reinterpret_cast<float4*>(out + baseP + i) = make_float4(0.f, 0.f, 0.f, 0.f);
  }
  const long baseQ = (long)bQ * (T_LEN * H_DIM);
  for (long i = (long)lenQ * H_DIM + tid * 4; i < (long)T_LEN * H_DIM; i += 512 * 4){
    *reinterpret_cast<float4*>(out + baseQ + i) = make_float4(0.f, 0.f, 0.f, 0.f);
  }
}

extern "C" void kernel_launch(void* const* d_in, const int* in_sizes, int n_in,
                              void* d_out, int out_size, void* d_ws, size_t ws_size,
                              hipStream_t stream){
  const float* x       = (const float*)d_in[0];
  const int*   lengths = (const int*)  d_in[1];
  const float* Wz = (const float*)d_in[2];
  const float* Uz = (const float*)d_in[3];
  const float* bz = (const float*)d_in[4];
  const float* Wr = (const float*)d_in[5];
  const float* Ur = (const float*)d_in[6];
  const float* br = (const float*)d_in[7];
  const float* Wh = (const float*)d_in[8];
  const float* Uh = (const float*)d_in[9];
  const float* bh = (const float*)d_in[10];

  unsigned int*   zr    = (unsigned int*)d_out;   // packed bf16 xz|xr, then h
  unsigned short* xhbuf = (unsigned short*)d_ws;  // bf16 xh

  gru_proj<<<dim3(2048), dim3(512), 0, stream>>>(x, Wz, Wr, Wh, bz, br, bh, zr, xhbuf);
  gru_rec2<<<dim3(64), dim3(512), 0, stream>>>(Uz, Ur, Uh, lengths, zr, xhbuf, (float*)d_out);
}

// Round 8
// 1248.840 us; speedup vs baseline: 1.4554x; 1.4554x over previous
//
#include <hip/hip_runtime.h>

// GRU: B=128, T=2048, H=128.
// Kernel 1 (gru_proj): xz/xr/xh = x @ W^T + b via bf16 MFMA 16x16x32.
//   xz,xr packed as 2x bf16 into d_out words (consumed then overwritten by h),
//   xh as bf16 into d_ws.
// Kernel 2 (gru_rec2w): 1 batch/block x 128 blocks, TWO waves x 64 units.
//   1 wave/SIMD -> zero issue-port contention; 2-wave barrier. Broadcast-A
//   MFMA matvecs, 4-chain accumulation x 4 independent tiles per gate.
//   Lane l owns unit 64w+l: epilogue = 1 value/lane, plain ds_write_b16
//   (2-way same-dword write is free, m136). z-MFMAs issue in phase A on
//   register h-frags, consumed in phase B (latency hidden under exchange).
//   2 lgkm-only barriers/step; 2-deep global prefetch + fire-and-forget
//   h stores (vmcnt never drained in loop).

#define T_LEN 2048
#define H_DIM 128

typedef __attribute__((ext_vector_type(8))) __bf16 bf16x8;
typedef __attribute__((ext_vector_type(4))) float f32x4;

// raw barrier: drains LDS ops (cross-wave visibility) but NOT vmcnt. [m201]
#define BARRIER() asm volatile("s_waitcnt lgkmcnt(0)\n\ts_barrier" ::: "memory")

__device__ __forceinline__ unsigned short f2bf_bits(float f){
  __bf16 b = (__bf16)f;                     // fptrunc, RNE
  return __builtin_bit_cast(unsigned short, b);
}
__device__ __forceinline__ float bf2f(unsigned short s){
  unsigned int u = ((unsigned int)s) << 16;
  return __builtin_bit_cast(float, u);
}
// hardware v_exp_f32 / v_rcp_f32 (no precise-division sequence)
__device__ __forceinline__ float sigm(float x){
  float e = __builtin_amdgcn_exp2f(-1.4426950408889634f * x);
  return __builtin_amdgcn_rcpf(1.0f + e);
}
__device__ __forceinline__ float tanh_fast(float x){
  float e = __builtin_amdgcn_exp2f(2.8853900817779268f * x);  // e^(2x)
  return 1.0f - 2.0f * __builtin_amdgcn_rcpf(e + 1.0f);       // inf-safe
}

// ---------------- projection GEMM (unchanged, verified) ----------------

__device__ __forceinline__ void stage_mat128(const float* __restrict__ src,
                                             __bf16 (*dst)[136], int tid){
  #pragma unroll
  for (int rep = 0; rep < 8; ++rep){
    int fi = rep * 2048 + tid * 4;
    float4 v = *reinterpret_cast<const float4*>(src + fi);
    int m = fi >> 7;
    int k = fi & 127;
    unsigned long long pk =
        (unsigned long long)f2bf_bits(v.x)
      | ((unsigned long long)f2bf_bits(v.y) << 16)
      | ((unsigned long long)f2bf_bits(v.z) << 32)
      | ((unsigned long long)f2bf_bits(v.w) << 48);
    *reinterpret_cast<unsigned long long*>(&dst[m][k]) = pk;
  }
}

__global__ __launch_bounds__(512, 2) void gru_proj(
    const float* __restrict__ x,
    const float* __restrict__ Wz, const float* __restrict__ Wr, const float* __restrict__ Wh,
    const float* __restrict__ bz, const float* __restrict__ br, const float* __restrict__ bh,
    unsigned int* __restrict__ out_zr, unsigned short* __restrict__ out_h)
{
  __shared__ __bf16 xs[128][136];
  __shared__ __bf16 wsh[3][128][136];

  const int tid = threadIdx.x;
  const long Mbase = (long)blockIdx.x * 128;

  stage_mat128(x + Mbase * H_DIM, xs, tid);
  stage_mat128(Wz, wsh[0], tid);
  stage_mat128(Wr, wsh[1], tid);
  stage_mat128(Wh, wsh[2], tid);
  __syncthreads();

  const int w  = tid >> 6, l = tid & 63;
  const int ml = l & 15;
  const int kl = (l >> 4) * 8;
  const int n  = w * 16 + ml;

  bf16x8 bfr[3][4];
  #pragma unroll
  for (int g = 0; g < 3; ++g)
    #pragma unroll
    for (int kk = 0; kk < 4; ++kk)
      bfr[g][kk] = *reinterpret_cast<const bf16x8*>(&wsh[g][n][kk * 32 + kl]);

  const float bzv = bz[n], brv = br[n], bhv = bh[n];

  f32x4 acc[8][3];
  #pragma unroll
  for (int mt = 0; mt < 8; ++mt)
    #pragma unroll
    for (int g = 0; g < 3; ++g)
      acc[mt][g] = (f32x4){0.f, 0.f, 0.f, 0.f};

  #pragma unroll
  for (int mt = 0; mt < 8; ++mt){
    #pragma unroll
    for (int kk = 0; kk < 4; ++kk){
      bf16x8 a = *reinterpret_cast<const bf16x8*>(&xs[mt * 16 + ml][kk * 32 + kl]);
      acc[mt][0] = __builtin_amdgcn_mfma_f32_16x16x32_bf16(a, bfr[0][kk], acc[mt][0], 0, 0, 0);
      acc[mt][1] = __builtin_amdgcn_mfma_f32_16x16x32_bf16(a, bfr[1][kk], acc[mt][1], 0, 0, 0);
      acc[mt][2] = __builtin_amdgcn_mfma_f32_16x16x32_bf16(a, bfr[2][kk], acc[mt][2], 0, 0, 0);
    }
  }

  #pragma unroll
  for (int mt = 0; mt < 8; ++mt){
    #pragma unroll
    for (int p = 0; p < 4; ++p){
      long row = Mbase + mt * 16 + (l >> 4) * 4 + p;
      float vz = acc[mt][0][p] + bzv;
      float vr = acc[mt][1][p] + brv;
      float vh = acc[mt][2][p] + bhv;
      unsigned int word = (unsigned int)f2bf_bits(vz)
                        | (((unsigned int)f2bf_bits(vr)) << 16);
      out_zr[row * H_DIM + n] = word;
      out_h [row * H_DIM + n] = f2bf_bits(vh);
    }
  }
}

// -------- recurrence: broadcast-A MFMA, 2 waves x 64 units, 1 batch/block ----

__device__ __forceinline__ bf16x8 ld_u_frag(const float* p){
  float4 a = *reinterpret_cast<const float4*>(p);
  float4 b = *reinterpret_cast<const float4*>(p + 4);
  bf16x8 r;
  r[0]=(__bf16)a.x; r[1]=(__bf16)a.y; r[2]=(__bf16)a.z; r[3]=(__bf16)a.w;
  r[4]=(__bf16)b.x; r[5]=(__bf16)b.y; r[6]=(__bf16)b.z; r[7]=(__bf16)b.w;
  return r;
}

#define MFMA(A, B, C) __builtin_amdgcn_mfma_f32_16x16x32_bf16(A, B, C, 0, 0, 0)

__device__ __forceinline__ void gru_step2w(
    int t, int ub, int g8, int u,
    const bf16x8 (*ufz)[4], const bf16x8 (*ufr)[4], const bf16x8 (*ufh)[4],
    __bf16* hx, __bf16* rhx,
    const unsigned int* xzr, const unsigned short* xh, float* out,
    unsigned int& zrw, unsigned short& xhw, float& h_own)
{
  const f32x4 zero = (f32x4){0.f, 0.f, 0.f, 0.f};
  const int tp = (t + 2 < T_LEN) ? t + 2 : T_LEN - 1;

  // ---- phase A ----
  bf16x8 a0 = *reinterpret_cast<const bf16x8*>(&hx[      g8 * 8]);
  bf16x8 a1 = *reinterpret_cast<const bf16x8*>(&hx[32  + g8 * 8]);
  bf16x8 a2 = *reinterpret_cast<const bf16x8*>(&hx[64  + g8 * 8]);
  bf16x8 a3 = *reinterpret_cast<const bf16x8*>(&hx[96  + g8 * 8]);

  // r gate: 4 independent tile-chains, 4-deep accumulation each
  f32x4 r0 = MFMA(a0, ufr[0][0], zero);
  f32x4 r1 = MFMA(a0, ufr[1][0], zero);
  f32x4 r2 = MFMA(a0, ufr[2][0], zero);
  f32x4 r3 = MFMA(a0, ufr[3][0], zero);
  r0 = MFMA(a1, ufr[0][1], r0);  r1 = MFMA(a1, ufr[1][1], r1);
  r2 = MFMA(a1, ufr[2][1], r2);  r3 = MFMA(a1, ufr[3][1], r3);
  r0 = MFMA(a2, ufr[0][2], r0);  r1 = MFMA(a2, ufr[1][2], r1);
  r2 = MFMA(a2, ufr[2][2], r2);  r3 = MFMA(a2, ufr[3][2], r3);
  r0 = MFMA(a3, ufr[0][3], r0);  r1 = MFMA(a3, ufr[1][3], r1);
  r2 = MFMA(a3, ufr[2][3], r2);  r3 = MFMA(a3, ufr[3][3], r3);

  float xzv = bf2f((unsigned short)(zrw & 0xffffu));   // keep for phase B
  float xrv = bf2f((unsigned short)(zrw >> 16));
  zrw = xzr[ub + tp * H_DIM];                          // refill for t+2

  float yr = r0[0];
  yr = (g8 == 1) ? r1[0] : yr;                         // cndmask select
  yr = (g8 == 2) ? r2[0] : yr;
  yr = (g8 == 3) ? r3[0] : yr;
  float rg = sigm(xrv + yr);
  rhx[u] = (__bf16)(rg * h_own);                       // all-lane b16 write

  // z gate: issue now (register inputs), consume after barrier
  f32x4 z0 = MFMA(a0, ufz[0][0], zero);
  f32x4 z1 = MFMA(a0, ufz[1][0], zero);
  f32x4 z2 = MFMA(a0, ufz[2][0], zero);
  f32x4 z3 = MFMA(a0, ufz[3][0], zero);
  z0 = MFMA(a1, ufz[0][1], z0);  z1 = MFMA(a1, ufz[1][1], z1);
  z2 = MFMA(a1, ufz[2][1], z2);  z3 = MFMA(a1, ufz[3][1], z3);
  z0 = MFMA(a2, ufz[0][2], z0);  z1 = MFMA(a2, ufz[1][2], z1);
  z2 = MFMA(a2, ufz[2][2], z2);  z3 = MFMA(a2, ufz[3][2], z3);
  z0 = MFMA(a3, ufz[0][3], z0);  z1 = MFMA(a3, ufz[1][3], z1);
  z2 = MFMA(a3, ufz[2][3], z2);  z3 = MFMA(a3, ufz[3][3], z3);

  BARRIER();                                           // rh visible

  // ---- phase B ----
  bf16x8 b0 = *reinterpret_cast<const bf16x8*>(&rhx[      g8 * 8]);
  bf16x8 b1 = *reinterpret_cast<const bf16x8*>(&rhx[32  + g8 * 8]);
  bf16x8 b2 = *reinterpret_cast<const bf16x8*>(&rhx[64  + g8 * 8]);
  bf16x8 b3 = *reinterpret_cast<const bf16x8*>(&rhx[96  + g8 * 8]);

  // zg: VALU work during rh read latency
  float yz = z0[0];
  yz = (g8 == 1) ? z1[0] : yz;
  yz = (g8 == 2) ? z2[0] : yz;
  yz = (g8 == 3) ? z3[0] : yz;
  float zg = sigm(xzv + yz);

  f32x4 h0 = MFMA(b0, ufh[0][0], zero);
  f32x4 h1 = MFMA(b0, ufh[1][0], zero);
  f32x4 h2 = MFMA(b0, ufh[2][0], zero);
  f32x4 h3 = MFMA(b0, ufh[3][0], zero);
  h0 = MFMA(b1, ufh[0][1], h0);  h1 = MFMA(b1, ufh[1][1], h1);
  h2 = MFMA(b1, ufh[2][1], h2);  h3 = MFMA(b1, ufh[3][1], h3);
  h0 = MFMA(b2, ufh[0][2], h0);  h1 = MFMA(b2, ufh[1][2], h1);
  h2 = MFMA(b2, ufh[2][2], h2);  h3 = MFMA(b2, ufh[3][2], h3);
  h0 = MFMA(b3, ufh[0][3], h0);  h1 = MFMA(b3, ufh[1][3], h1);
  h2 = MFMA(b3, ufh[2][3], h2);  h3 = MFMA(b3, ufh[3][3], h3);

  float yh = h0[0];
  yh = (g8 == 1) ? h1[0] : yh;
  yh = (g8 == 2) ? h2[0] : yh;
  yh = (g8 == 3) ? h3[0] : yh;
  float hc = tanh_fast(bf2f(xhw) + yh);
  float hn = fmaf(zg, hc - h_own, h_own);              // (1-z)h + z*hc
  h_own = hn;
  hx[u] = (__bf16)hn;                                  // all-lane b16 write
  out[ub + t * H_DIM] = hn;                            // fire-and-forget
  xhw = xh[ub + tp * H_DIM];                           // refill for t+2
  BARRIER();                                           // h' visible
}

__global__ __launch_bounds__(128, 1) void gru_rec2w(
    const float* __restrict__ Uz, const float* __restrict__ Ur, const float* __restrict__ Uh,
    const int* __restrict__ lengths,
    const unsigned int* xzr,            // aliases `out` (packed bf16 xz|xr)
    const unsigned short* __restrict__ xh,
    float* out)
{
  __shared__ __align__(16) __bf16 hx[H_DIM];
  __shared__ __align__(16) __bf16 rhx[H_DIM];

  const int tid = threadIdx.x;
  const int w = tid >> 6, l = tid & 63;
  const int g8 = l >> 4;                // k-slice within each 32-k block
  const int u  = w * 64 + l;            // owned unit
  const int b  = blockIdx.x;
  const int len = lengths[b];

  // U B-fragments: 3 gates x 4 tiles x 4 chunks x 4 VGPR = 192 VGPRs
  // tile t covers units [64w+16t, 64w+16t+16); this lane's B-col = l&15
  bf16x8 ufz[4][4], ufr[4][4], ufh[4][4];
  #pragma unroll
  for (int t4 = 0; t4 < 4; ++t4){
    const int n = w * 64 + t4 * 16 + (l & 15);
    #pragma unroll
    for (int c = 0; c < 4; ++c){
      const int ko = c * 32 + g8 * 8;
      ufz[t4][c] = ld_u_frag(Uz + n * H_DIM + ko);
      ufr[t4][c] = ld_u_frag(Ur + n * H_DIM + ko);
      ufh[t4][c] = ld_u_frag(Uh + n * H_DIM + ko);
    }
  }

  if (tid < 64) reinterpret_cast<unsigned int*>(hx)[tid] = 0u;  // h0 = 0
  float h_own = 0.f;
  __syncthreads();

  const int ub = b * (T_LEN * H_DIM) + u;

  // 2-deep prefetch, named regs
  unsigned int  zrA = xzr[ub],         zrB = xzr[ub + H_DIM];
  unsigned short xhA = xh[ub],         xhB = xh[ub + H_DIM];

  int t = 0;
  for (; t + 1 < len; t += 2){
    gru_step2w(t,   ub, g8, u, ufz, ufr, ufh, hx, rhx, xzr, xh, out, zrA, xhA, h_own);
    gru_step2w(t+1, ub, g8, u, ufz, ufr, ufh, hx, rhx, xzr, xh, out, zrB, xhB, h_own);
  }
  if (t < len){
    gru_step2w(t,   ub, g8, u, ufz, ufr, ufh, hx, rhx, xzr, xh, out, zrA, xhA, h_own);
  }

  // masked region: exact zeros for t >= len (disjoint from h-stores)
  const long base = (long)b * (T_LEN * H_DIM);
  for (long i = (long)len * H_DIM + tid * 4; i < (long)T_LEN * H_DIM; i += 128 * 4){
    *reinterpret_cast<float4*>(out + base + i) = make_float4(0.f, 0.f, 0.f, 0.f);
  }
}

extern "C" void kernel_launch(void* const* d_in, const int* in_sizes, int n_in,
                              void* d_out, int out_size, void* d_ws, size_t ws_size,
                              hipStream_t stream){
  const float* x       = (const float*)d_in[0];
  const int*   lengths = (const int*)  d_in[1];
  const float* Wz = (const float*)d_in[2];
  const float* Uz = (const float*)d_in[3];
  const float* bz = (const float*)d_in[4];
  const float* Wr = (const float*)d_in[5];
  const float* Ur = (const float*)d_in[6];
  const float* br = (const float*)d_in[7];
  const float* Wh = (const float*)d_in[8];
  const float* Uh = (const float*)d_in[9];
  const float* bh = (const float*)d_in[10];

  unsigned int*   zr    = (unsigned int*)d_out;   // packed bf16 xz|xr, then h
  unsigned short* xhbuf = (unsigned short*)d_ws;  // bf16 xh

  gru_proj<<<dim3(2048), dim3(512), 0, stream>>>(x, Wz, Wr, Wh, bz, br, bh, zr, xhbuf);
  gru_rec2w<<<dim3(128), dim3(128), 0, stream>>>(Uz, Ur, Uh, lengths, zr, xhbuf, (float*)d_out);
}